// Round 5
// baseline (7561.054 us; speedup 1.0000x reference)
//
#include <hip/hip_runtime.h>
#include <hip/hip_bf16.h>

// PeepholeLSTM: SEQ=512, BATCH=64, IN=512, HS=1024, FORGET_BIAS=0
// out = [hidden_seq (512*64*1024) | c_T (64*1024) | h_T (64*1024)] f32
//
//  prep_w  : W f32 -> WxPT bf16 [4096 n][512 k] (perm cols) + WhP bf16 [64 g][128 kb][64 c][8 e]
//  gemm_x  : XP[t][g][m][c] bf16 = (x @ Wx)   (128x128 tile MFMA GEMM)
//  lstm_seq: persistent 64 WGs x 4 independent waves. Cross-WG h exchange:
//    data  = 1 u64 exchange/lane (4 bf16, executes at LLC), loaded once via agent-scope
//            atomic loads (LLC-coherent, bypasses stale L1/L2);
//    ready = 256 per-WAVE flags; producer: exchange h -> s_waitcnt vmcnt(0) -> flag
//            exchange; consumer: poll 2 u64/lane (all 256 flags) then load data ONCE.
//    Round-4 lesson: polling tags on the data itself forced full 512B/lane reloads per
//    retry round (~4us/step). Flag poll rounds are 16B/lane; data is never re-fetched.
//    4-deep buffer rotation + poll-gates-write => no overwrite-before-read.

#define SEQN 512
#define BATCH 64
#define INDIM 512
#define HSZ 1024

typedef __attribute__((ext_vector_type(8))) short s16x8;
typedef __attribute__((ext_vector_type(4))) short s16x4;
typedef __attribute__((ext_vector_type(4))) float f32x4;
typedef unsigned long long u64;

__device__ __forceinline__ short f2bf(float f) {
  __hip_bfloat16 b = __float2bfloat16(f);
  short s;
  __builtin_memcpy(&s, &b, 2);
  return s;
}
__device__ __forceinline__ float bf2f(short s) {
  unsigned u = ((unsigned)(unsigned short)s) << 16;
  float f;
  __builtin_memcpy(&f, &u, 4);
  return f;
}
__device__ __forceinline__ float sigf(float x) { return 1.f / (1.f + __expf(-x)); }
__device__ __forceinline__ float tanh_fast(float x) { return 2.f / (1.f + __expf(-2.f * x)) - 1.f; }

// ---------------------------------------------------------------------------
// prep_w: col = gate*1024 + g*16 + off  ->  permuted n = g*64 + gate*16 + off
__global__ __launch_bounds__(256) void prep_w(const float* __restrict__ W,
                                              short* __restrict__ WxPT,
                                              short* __restrict__ WhP) {
  int idx = blockIdx.x * 256 + threadIdx.x;
  if (idx >= 1536 * 4096) return;
  int k = idx >> 12, col = idx & 4095;
  short b = f2bf(W[idx]);
  int gate = col >> 10, rem = col & 1023, g = rem >> 4, off = rem & 15;
  int c = gate * 16 + off;
  if (k < 512) {
    int n = g * 64 + c;
    WxPT[(size_t)n * 512 + k] = b;
  } else {
    int kh = k - 512;
    WhP[(size_t)(((g * 128 + (kh >> 3)) * 64 + c) << 3) + (kh & 7)] = b;
  }
}

// ---------------------------------------------------------------------------
// gemm_x: M=32768 (t*64+b), N=4096 (perm cols), K=512. BM=BN=128, BK=32.
// Output XP[t][g][m 64][c 64] bf16.
__global__ __launch_bounds__(256) void gemm_x(const float* __restrict__ x,
                                              const short* __restrict__ WxPT,
                                              short* __restrict__ XP) {
  __shared__ short As[4096];
  __shared__ short Bs[4096];
  int tid = threadIdx.x;
  int w = tid >> 6, l = tid & 63;
  int mt = blockIdx.x >> 5, nt = blockIdx.x & 31;
  int m0 = mt * 128, n0 = nt * 128;
  f32x4 acc[4][4];
#pragma unroll
  for (int a = 0; a < 4; ++a)
#pragma unroll
    for (int b = 0; b < 4; ++b) acc[a][b] = (f32x4){0.f, 0.f, 0.f, 0.f};

  for (int ks = 0; ks < 16; ++ks) {
    int k0 = ks * 32;
#pragma unroll
    for (int it = 0; it < 2; ++it) {
      int cchunk = it * 256 + tid;  // 512 chunks of 16B
      int kb = cchunk >> 7, rc = cchunk & 127;
      const float4* ap = reinterpret_cast<const float4*>(x + (size_t)(m0 + rc) * 512 + k0 + kb * 8);
      float4 fa = ap[0], fb = ap[1];
      s16x8 av;
      av[0] = f2bf(fa.x); av[1] = f2bf(fa.y); av[2] = f2bf(fa.z); av[3] = f2bf(fa.w);
      av[4] = f2bf(fb.x); av[5] = f2bf(fb.y); av[6] = f2bf(fb.z); av[7] = f2bf(fb.w);
      s16x8 bv = *reinterpret_cast<const s16x8*>(WxPT + (size_t)(n0 + rc) * 512 + k0 + kb * 8);
      reinterpret_cast<s16x8*>(As)[cchunk] = av;
      reinterpret_cast<s16x8*>(Bs)[cchunk] = bv;
    }
    __syncthreads();
    s16x8 af[4], bfr[4];
#pragma unroll
    for (int tm = 0; tm < 4; ++tm)
      af[tm] = reinterpret_cast<s16x8*>(As)[(l >> 4) * 128 + (w >> 1) * 64 + tm * 16 + (l & 15)];
#pragma unroll
    for (int tn = 0; tn < 4; ++tn)
      bfr[tn] = reinterpret_cast<s16x8*>(Bs)[(l >> 4) * 128 + (w & 1) * 64 + tn * 16 + (l & 15)];
#pragma unroll
    for (int tm = 0; tm < 4; ++tm)
#pragma unroll
      for (int tn = 0; tn < 4; ++tn)
        acc[tm][tn] = __builtin_amdgcn_mfma_f32_16x16x32_bf16(af[tm], bfr[tn], acc[tm][tn], 0, 0, 0);
    __syncthreads();
  }
#pragma unroll
  for (int tm = 0; tm < 4; ++tm)
#pragma unroll
    for (int tn = 0; tn < 4; ++tn)
#pragma unroll
      for (int r = 0; r < 4; ++r) {
        int m = m0 + (w >> 1) * 64 + tm * 16 + (l >> 4) * 4 + r;
        int n = n0 + (w & 1) * 64 + tn * 16 + (l & 15);
        XP[(size_t)(m >> 6) * 262144 + (size_t)(n >> 6) * 4096 + (m & 63) * 64 + (n & 63)] =
            f2bf(acc[tm][tn][r]);
      }
}

// ---------------------------------------------------------------------------
// lstm_seq: 64 WGs x 256. WG g owns hidden [16g,16g+16) (perm-cols [64g,64g+64)).
// Wave w owns batch rows [16w,16w+16); lane l: m = w*16+(l&15), hcol0 = g*16+(l>>4)*4.
// h buffer: hq[t&3][m 0..63][u64 col-quad 0..255], u64 = 4 bf16 (cols 4q..4q+3).
// flags[256]: flags[g*4+w] = number of steps wave (g,w) has published.
__global__ __launch_bounds__(256, 1) void lstm_seq(const short* __restrict__ XP,
                                                   const short* __restrict__ WhP,
                                                   const float* __restrict__ bias,
                                                   const float* __restrict__ peep_i,
                                                   const float* __restrict__ peep_f,
                                                   const float* __restrict__ peep_o,
                                                   u64* hq,
                                                   unsigned* flags,
                                                   float* __restrict__ out) {
  __shared__ short WhS[65536];  // 128KB
  int g = blockIdx.x;
  int tid = threadIdx.x, w = tid >> 6, l = tid & 63;
  const short* wsrc = WhP + (size_t)g * 65536;
#pragma unroll 4
  for (int it = 0; it < 32; ++it) {
    int cchunk = it * 256 + tid;
    reinterpret_cast<s16x8*>(WhS)[cchunk] = *reinterpret_cast<const s16x8*>(wsrc + cchunk * 8);
  }
  int m = w * 16 + (l & 15);
  int q4 = l >> 4;
  int hcol0 = g * 16 + (q4 << 2);
  f32x4 bi4 = *reinterpret_cast<const f32x4*>(bias + hcol0);
  f32x4 bj4 = *reinterpret_cast<const f32x4*>(bias + 1024 + hcol0);
  f32x4 bf4 = *reinterpret_cast<const f32x4*>(bias + 2048 + hcol0);
  f32x4 bo4 = *reinterpret_cast<const f32x4*>(bias + 3072 + hcol0);
  f32x4 pi4 = *reinterpret_cast<const f32x4*>(peep_i + hcol0);
  f32x4 pf4 = *reinterpret_cast<const f32x4*>(peep_f + hcol0);
  f32x4 po4 = *reinterpret_cast<const f32x4*>(peep_o + hcol0);
  float cr[4] = {0.f, 0.f, 0.f, 0.f};
  int fw = g * 4 + w;  // this wave's flag
  const u64* fq = reinterpret_cast<const u64*>(flags);
  s16x8* WhS16 = reinterpret_cast<s16x8*>(WhS);
  __syncthreads();

  for (int t = 0; t < SEQN; ++t) {
    // x-projection prefetch (plain cached loads; written by gemm_x, coherent at dispatch)
    const short* xpb = XP + ((size_t)t * 64 + g) * 4096 + m * 64 + (q4 << 2);
    s16x4 xg0 = *reinterpret_cast<const s16x4*>(xpb);
    s16x4 xg1 = *reinterpret_cast<const s16x4*>(xpb + 16);
    s16x4 xg2 = *reinterpret_cast<const s16x4*>(xpb + 32);
    s16x4 xg3 = *reinterpret_cast<const s16x4*>(xpb + 48);

    f32x4 acc0 = {0.f, 0.f, 0.f, 0.f}, acc1 = {0.f, 0.f, 0.f, 0.f};
    f32x4 acc2 = {0.f, 0.f, 0.f, 0.f}, acc3 = {0.f, 0.f, 0.f, 0.f};
    if (t > 0) {
      // --- detect: all 256 wave-flags >= t (16B/lane per round) ---
      {
        int guard = 0;
        while (true) {
          u64 f0 = __hip_atomic_load(fq + 2 * l, __ATOMIC_RELAXED, __HIP_MEMORY_SCOPE_AGENT);
          u64 f1 = __hip_atomic_load(fq + 2 * l + 1, __ATOMIC_RELAXED, __HIP_MEMORY_SCOPE_AGENT);
          unsigned a = (unsigned)f0, b = (unsigned)(f0 >> 32);
          unsigned c = (unsigned)f1, d = (unsigned)(f1 >> 32);
          unsigned mn = min(min(a, b), min(c, d));
          if (__all((int)(mn >= (unsigned)t))) break;
          if (++guard > (1 << 15)) break;  // fail loud (wrong data), never hang
        }
      }
      // --- load the lane's h panel ONCE: row m, 64 u64 (LLC-coherent atomic loads) ---
      const u64* rdq = hq + (size_t)(t & 3) * 16384 + m * 256;
      u64 hr[64];
#pragma unroll
      for (int kk = 0; kk < 32; ++kk) {
        hr[2 * kk] = __hip_atomic_load(rdq + kk * 8 + q4 * 2, __ATOMIC_RELAXED,
                                       __HIP_MEMORY_SCOPE_AGENT);
        hr[2 * kk + 1] = __hip_atomic_load(rdq + kk * 8 + q4 * 2 + 1, __ATOMIC_RELAXED,
                                           __HIP_MEMORY_SCOPE_AGENT);
      }
#pragma unroll
      for (int kk = 0; kk < 32; ++kk) {
        union { u64 q[2]; s16x8 v; } bu;
        bu.q[0] = hr[2 * kk];
        bu.q[1] = hr[2 * kk + 1];
        int kbl = (kk * 4 + q4) * 64 + (l & 15);
        s16x8 a0 = WhS16[kbl];
        s16x8 a1 = WhS16[kbl + 16];
        s16x8 a2 = WhS16[kbl + 32];
        s16x8 a3 = WhS16[kbl + 48];
        acc0 = __builtin_amdgcn_mfma_f32_16x16x32_bf16(a0, bu.v, acc0, 0, 0, 0);
        acc1 = __builtin_amdgcn_mfma_f32_16x16x32_bf16(a1, bu.v, acc1, 0, 0, 0);
        acc2 = __builtin_amdgcn_mfma_f32_16x16x32_bf16(a2, bu.v, acc2, 0, 0, 0);
        acc3 = __builtin_amdgcn_mfma_f32_16x16x32_bf16(a3, bu.v, acc3, 0, 0, 0);
      }
    }
    // elementwise: lane has gates i/j/f/o (acc0..3)[r] for hidden col hcol0+r, batch m
    f32x4 hv, cv;
    union { u64 q; short s[4]; } hp;
#pragma unroll
    for (int r = 0; r < 4; ++r) {
      float cold = cr[r];
      float gi = acc0[r] + bf2f(xg0[r]) + bi4[r];
      float gj = acc1[r] + bf2f(xg1[r]) + bj4[r];
      float gf = acc2[r] + bf2f(xg2[r]) + bf4[r];
      float go = acc3[r] + bf2f(xg3[r]) + bo4[r];
      float it_g = sigf(gi + cold * pi4[r]);
      float ft = sigf(gf + cold * pf4[r]);
      float cn = ft * cold + it_g * tanh_fast(gj);
      float ot = sigf(go + cn * po4[r]);
      float h = ot * tanh_fast(cn);
      cr[r] = cn;
      hp.s[r] = f2bf(h);
      hv[r] = h;
      cv[r] = cn;
    }
    // --- publish: h exchange (1 op) -> drain -> flag exchange ---
    {
      u64* wrq = hq + (size_t)((t + 1) & 3) * 16384;
      (void)__hip_atomic_exchange(wrq + m * 256 + g * 4 + q4, hp.q, __ATOMIC_RELAXED,
                                  __HIP_MEMORY_SCOPE_AGENT);
    }
    asm volatile("s_waitcnt vmcnt(0)" ::: "memory");
    if (l == 0)
      (void)__hip_atomic_exchange(&flags[fw], (unsigned)(t + 1), __ATOMIC_RELAXED,
                                  __HIP_MEMORY_SCOPE_AGENT);
    // out stores AFTER the flag: their ack latency is off the critical path
    __builtin_nontemporal_store(hv, reinterpret_cast<f32x4*>(out + (size_t)t * 65536 +
                                                             (size_t)m * 1024 + hcol0));
    if (t == SEQN - 1) {
      *reinterpret_cast<f32x4*>(out + 33554432ull + (size_t)m * 1024 + hcol0) = cv;  // c_T
      *reinterpret_cast<f32x4*>(out + 33619968ull + (size_t)m * 1024 + hcol0) = hv;  // h_T
    }
  }
}

// ---------------------------------------------------------------------------
extern "C" void kernel_launch(void* const* d_in, const int* in_sizes, int n_in,
                              void* d_out, int out_size, void* d_ws, size_t ws_size,
                              hipStream_t stream) {
  const float* x      = (const float*)d_in[0];
  const float* W      = (const float*)d_in[1];
  const float* bias   = (const float*)d_in[2];
  const float* peep_i = (const float*)d_in[3];
  const float* peep_f = (const float*)d_in[4];
  const float* peep_o = (const float*)d_in[5];
  char* ws = (char*)d_ws;
  short* XP   = (short*)(ws);                  // 268435456  bf16 gate pre-acts
  short* WxPT = (short*)(ws + 268435456ull);   //   4194304
  short* WhP  = (short*)(ws + 272629760ull);   //   8388608
  u64* hq     = (u64*)(ws + 281018368ull);     //    524288  (4 x 128KB h buffers)
  unsigned* flags = (unsigned*)(ws + 281542656ull);  // 1024 (256 per-wave flags)
  // zero flags every launch: leftover values from a previous replay would satisfy
  // this run's polls early, silently skipping synchronization
  hipMemsetAsync(flags, 0, 1024, stream);
  prep_w<<<24576, 256, 0, stream>>>(W, WxPT, WhP);
  gemm_x<<<8192, 256, 0, stream>>>(x, WxPT, XP);
  lstm_seq<<<64, 256, 0, stream>>>(XP, WhP, bias, peep_i, peep_f, peep_o, hq, flags,
                                   (float*)d_out);
}

// Round 7
// 4616.819 us; speedup vs baseline: 1.6377x; 1.6377x over previous
//
#include <hip/hip_runtime.h>
#include <hip/hip_bf16.h>

// PeepholeLSTM: SEQ=512, BATCH=64, IN=512, HS=1024, FORGET_BIAS=0
// out = [hidden_seq (512*64*1024) | c_T (64*1024) | h_T (64*1024)] f32
//
// Round-7 = round-6 structure with the compile fix (ext_vector float2 for nt-store).
//  prep_w : W f32 -> WxP bf16 [128 g][64 kb][32 pc][8] + WhP bf16 [128 g][128 kb][32 pc][8]
//           perm: W col = gate*1024 + (g*8+off)  ->  pc = off*4 + gate (lane gets all 4 gates)
//  prep_x : x f32 -> xbp bf16 [512 t][64 kb][64 m][8]  (MFMA B-frag friendly, 32MB, LLC-resident)
//  lstm_seq: 128 persistent WGs x 256. WG g owns hidden cols [8g, 8g+8).
//    LDS: Wh slice 64KB + Wx slice 32KB + 2KB out-staging = 98KB.
//    Per step: x-proj MFMAs (h-independent, hides latency) -> tagged-h consume
//    (tag32|2bf16 u64, agent-scope atomic loads, 4 pipelined groups of 32 u64,
//    retry = 256B/lane) -> elementwise -> 1 tagged u64 exchange/lane (fire-and-forget).
//    No fences, no flags, no __syncthreads in the step loop. 4-deep buffer rotation
//    (max skew 2 < 4 => no overwrite-before-read). Round-4 lesson: detection spread
//    over 256KB (no hot lines); round-5 lesson: no global flag convoy; XP-stream
//    removal stops LLC eviction of sync lines (FETCH_SIZE +264MB last time).

#define SEQN 512
#define BATCH 64
#define INDIM 512
#define HSZ 1024
#define NWG 128

typedef __attribute__((ext_vector_type(8))) short s16x8;
typedef __attribute__((ext_vector_type(4))) float f32x4;
typedef __attribute__((ext_vector_type(2))) float f32x2;
typedef unsigned long long u64;

__device__ __forceinline__ short f2bf(float f) {
  __hip_bfloat16 b = __float2bfloat16(f);
  short s;
  __builtin_memcpy(&s, &b, 2);
  return s;
}
__device__ __forceinline__ float sigf(float x) { return 1.f / (1.f + __expf(-x)); }
__device__ __forceinline__ float tanh_fast(float x) { return 2.f / (1.f + __expf(-2.f * x)) - 1.f; }

// ---------------------------------------------------------------------------
// prep_w: one thread per W element. col = gate*1024 + hidx; hidx = g*8+off; pc = off*4+gate.
__global__ __launch_bounds__(256) void prep_w(const float* __restrict__ W,
                                              short* __restrict__ WxP,
                                              short* __restrict__ WhP) {
  int idx = blockIdx.x * 256 + threadIdx.x;
  if (idx >= 1536 * 4096) return;
  int k = idx >> 12, col = idx & 4095;
  short b = f2bf(W[idx]);
  int gate = col >> 10, hidx = col & 1023;
  int g = hidx >> 3, off = hidx & 7;
  int pc = off * 4 + gate;
  if (k < 512) {
    WxP[(size_t)(((g * 64 + (k >> 3)) * 32 + pc) << 3) + (k & 7)] = b;
  } else {
    int kh = k - 512;
    WhP[(size_t)(((g * 128 + (kh >> 3)) * 32 + pc) << 3) + (kh & 7)] = b;
  }
}

// ---------------------------------------------------------------------------
// prep_x: x[t][m][k] f32 -> xbp[t][kb][m][8] bf16. One thread per (t,m,kb): reads 32B.
__global__ __launch_bounds__(256) void prep_x(const float* __restrict__ x,
                                              short* __restrict__ xbp) {
  int idx = blockIdx.x * 256 + threadIdx.x;
  if (idx >= SEQN * 64 * 64) return;
  int kb = idx & 63, m = (idx >> 6) & 63, t = idx >> 12;
  const float4* xp = reinterpret_cast<const float4*>(x + ((size_t)t * 64 + m) * 512 + kb * 8);
  float4 a = xp[0], c = xp[1];
  s16x8 v;
  v[0] = f2bf(a.x); v[1] = f2bf(a.y); v[2] = f2bf(a.z); v[3] = f2bf(a.w);
  v[4] = f2bf(c.x); v[5] = f2bf(c.y); v[6] = f2bf(c.z); v[7] = f2bf(c.w);
  reinterpret_cast<s16x8*>(xbp)[((size_t)t * 64 + kb) * 64 + m] = v;
}

// ---------------------------------------------------------------------------
// lstm_seq: 128 WGs x 256. WG g: hidden [8g,8g+8), perm-cols pc=off*4+gate (32).
// Wave w: batch rows [16w,16w+16). Lane l: m = w*16+(l&15), q4 = l>>4,
//   owns hidden cols c0 = 8g+q4, c1 = 8g+q4+4, all 4 gates (acc0[r]=gate r @ c0, acc1 @ c1).
// Tagged h: hqt[t&3][gsrc 0..127][m 0..63][j 0..3] u64 = tag(t)<<32 | h[8gsrc+j+4]<<16 | h[8gsrc+j].
__global__ __launch_bounds__(256, 1) void lstm_seq(const short* __restrict__ xbp,
                                                   const short* __restrict__ WhP,
                                                   const short* __restrict__ WxP,
                                                   const float* __restrict__ bias,
                                                   const float* __restrict__ peep_i,
                                                   const float* __restrict__ peep_f,
                                                   const float* __restrict__ peep_o,
                                                   u64* hqt,
                                                   float* __restrict__ out) {
  __shared__ short WhS[32768];   // 64KB [kb 128][pc 32][8]
  __shared__ short WxS[16384];   // 32KB [kb  64][pc 32][8]
  __shared__ float outS[512];    //  2KB [wave 4][mrow 16][col 8]
  int g = blockIdx.x;
  int tid = threadIdx.x, w = tid >> 6, l = tid & 63;
  {
    const s16x8* src = reinterpret_cast<const s16x8*>(WhP + (size_t)g * 32768);
    s16x8* dst = reinterpret_cast<s16x8*>(WhS);
#pragma unroll
    for (int i = 0; i < 16; ++i) dst[i * 256 + tid] = src[i * 256 + tid];
    const s16x8* src2 = reinterpret_cast<const s16x8*>(WxP + (size_t)g * 16384);
    s16x8* dst2 = reinterpret_cast<s16x8*>(WxS);
#pragma unroll
    for (int i = 0; i < 8; ++i) dst2[i * 256 + tid] = src2[i * 256 + tid];
  }
  int m = w * 16 + (l & 15), q4 = l >> 4, l15 = l & 15;
  int c0 = g * 8 + q4, c1 = c0 + 4;
  float bi0 = bias[c0], bj0 = bias[1024 + c0], bf0 = bias[2048 + c0], bo0 = bias[3072 + c0];
  float bi1 = bias[c1], bj1 = bias[1024 + c1], bf1 = bias[2048 + c1], bo1 = bias[3072 + c1];
  float pi0 = peep_i[c0], pf0 = peep_f[c0], po0 = peep_o[c0];
  float pi1 = peep_i[c1], pf1 = peep_f[c1], po1 = peep_o[c1];
  float cr0 = 0.f, cr1 = 0.f;
  s16x8* WhS16 = reinterpret_cast<s16x8*>(WhS);
  s16x8* WxS16 = reinterpret_cast<s16x8*>(WxS);
  __syncthreads();

// group G (8 kk-blocks): 32 u64/lane; i=0..31: kb=(G*8+(i>>2))*4+q4, j=i&3
#define LOADG(BANK, G)                                                                  \
  {                                                                                     \
    _Pragma("unroll") for (int i = 0; i < 32; ++i) {                                    \
      int kb_ = ((G) * 8 + (i >> 2)) * 4 + q4;                                          \
      BANK[i] = __hip_atomic_load(rdq + kb_ * 256 + m * 4 + (i & 3), __ATOMIC_RELAXED,  \
                                  __HIP_MEMORY_SCOPE_AGENT);                            \
    }                                                                                   \
  }
#define CHECKG(BANK, G)                                                                 \
  {                                                                                     \
    int guard = 0;                                                                      \
    while (true) {                                                                      \
      bool ok = true;                                                                   \
      _Pragma("unroll") for (int i = 0; i < 32; ++i) ok &=                              \
          ((unsigned)(BANK[i] >> 32) == (unsigned)t);                                   \
      if (__all((int)ok)) break;                                                        \
      if (++guard > (1 << 14)) break; /* fail loud, never hang */                       \
      LOADG(BANK, G);                                                                   \
    }                                                                                   \
  }
#define MFMAG(BANK, G)                                                                  \
  {                                                                                     \
    _Pragma("unroll") for (int kk2 = 0; kk2 < 8; ++kk2) {                               \
      int kb_ = ((G) * 8 + kk2) * 4 + q4;                                               \
      unsigned d0 = (unsigned)BANK[kk2 * 4 + 0], d1 = (unsigned)BANK[kk2 * 4 + 1];      \
      unsigned d2 = (unsigned)BANK[kk2 * 4 + 2], d3 = (unsigned)BANK[kk2 * 4 + 3];      \
      union { unsigned u[4]; s16x8 v; } bu;                                             \
      bu.u[0] = (d0 & 0xFFFFu) | (d1 << 16);                                            \
      bu.u[1] = (d2 & 0xFFFFu) | (d3 << 16);                                            \
      bu.u[2] = (d0 >> 16) | (d1 & 0xFFFF0000u);                                        \
      bu.u[3] = (d2 >> 16) | (d3 & 0xFFFF0000u);                                       \
      s16x8 a0 = WhS16[kb_ * 32 + l15];                                                 \
      s16x8 a1 = WhS16[kb_ * 32 + 16 + l15];                                            \
      acc0 = __builtin_amdgcn_mfma_f32_16x16x32_bf16(a0, bu.v, acc0, 0, 0, 0);          \
      acc1 = __builtin_amdgcn_mfma_f32_16x16x32_bf16(a1, bu.v, acc1, 0, 0, 0);          \
    }                                                                                   \
  }

  for (int t = 0; t < SEQN; ++t) {
    f32x4 acc0 = {0.f, 0.f, 0.f, 0.f}, acc1 = {0.f, 0.f, 0.f, 0.f};
    // ---- x-projection (h-independent; fills the latency window) ----
    {
      const s16x8* xt = reinterpret_cast<const s16x8*>(xbp) + (size_t)t * 4096;
#pragma unroll 4
      for (int kk = 0; kk < 16; ++kk) {
        int kb = kk * 4 + q4;
        s16x8 bx = xt[kb * 64 + m];
        s16x8 a0 = WxS16[kb * 32 + l15];
        s16x8 a1 = WxS16[kb * 32 + 16 + l15];
        acc0 = __builtin_amdgcn_mfma_f32_16x16x32_bf16(a0, bx, acc0, 0, 0, 0);
        acc1 = __builtin_amdgcn_mfma_f32_16x16x32_bf16(a1, bx, acc1, 0, 0, 0);
      }
    }
    // ---- recurrent part: tagged-h consume, 4 groups pipelined ----
    if (t > 0) {
      const u64* rdq = hqt + (size_t)(t & 3) * 32768;
      u64 hA[32], hB[32];
      LOADG(hA, 0);
      LOADG(hB, 1);
      CHECKG(hA, 0);
      MFMAG(hA, 0);
      LOADG(hA, 2);
      CHECKG(hB, 1);
      MFMAG(hB, 1);
      LOADG(hB, 3);
      CHECKG(hA, 2);
      MFMAG(hA, 2);
      CHECKG(hB, 3);
      MFMAG(hB, 3);
    }
    // ---- elementwise (lane-local: all 4 gates of c0 and c1) ----
    float i0 = sigf(acc0[0] + bi0 + cr0 * pi0);
    float f0 = sigf(acc0[2] + bf0 + cr0 * pf0);
    float cn0 = f0 * cr0 + i0 * tanh_fast(acc0[1] + bj0);
    float o0 = sigf(acc0[3] + bo0 + cn0 * po0);
    float h0 = o0 * tanh_fast(cn0);
    cr0 = cn0;
    float i1 = sigf(acc1[0] + bi1 + cr1 * pi1);
    float f1 = sigf(acc1[2] + bf1 + cr1 * pf1);
    float cn1 = f1 * cr1 + i1 * tanh_fast(acc1[1] + bj1);
    float o1 = sigf(acc1[3] + bo1 + cn1 * po1);
    float h1 = o1 * tanh_fast(cn1);
    cr1 = cn1;
    // ---- publish tagged h_t (tag t+1) into buf (t+1)&3: ONE exchange/lane ----
    {
      u64 q = ((u64)(unsigned)(t + 1) << 32) |
              ((u64)(unsigned short)f2bf(h1) << 16) | (u64)(unsigned short)f2bf(h0);
      (void)__hip_atomic_exchange(hqt + (size_t)((t + 1) & 3) * 32768 + g * 256 + m * 4 + q4,
                                  q, __ATOMIC_RELAXED, __HIP_MEMORY_SCOPE_AGENT);
    }
    // ---- coalesced hidden_seq store via wave-local LDS stage ----
    outS[w * 128 + l15 * 8 + q4] = h0;
    outS[w * 128 + l15 * 8 + q4 + 4] = h1;
    // same-wave ds_write -> ds_read: compiler inserts lgkmcnt; wave is lockstep
    {
      f32x2 v = *reinterpret_cast<f32x2*>(&outS[w * 128 + (l >> 2) * 8 + (l & 3) * 2]);
      int row = w * 16 + (l >> 2), col = g * 8 + (l & 3) * 2;
      __builtin_nontemporal_store(
          v, reinterpret_cast<f32x2*>(out + (size_t)t * 65536 + (size_t)row * 1024 + col));
    }
    if (t == SEQN - 1) {
      out[33554432ull + (size_t)m * 1024 + c0] = cn0;  // c_T
      out[33554432ull + (size_t)m * 1024 + c1] = cn1;
      out[33619968ull + (size_t)m * 1024 + c0] = h0;   // h_T
      out[33619968ull + (size_t)m * 1024 + c1] = h1;
    }
  }
#undef LOADG
#undef CHECKG
#undef MFMAG
}

// ---------------------------------------------------------------------------
extern "C" void kernel_launch(void* const* d_in, const int* in_sizes, int n_in,
                              void* d_out, int out_size, void* d_ws, size_t ws_size,
                              hipStream_t stream) {
  const float* x      = (const float*)d_in[0];
  const float* W      = (const float*)d_in[1];
  const float* bias   = (const float*)d_in[2];
  const float* peep_i = (const float*)d_in[3];
  const float* peep_f = (const float*)d_in[4];
  const float* peep_o = (const float*)d_in[5];
  char* ws = (char*)d_ws;
  short* WxP = (short*)(ws);                   //  4194304 B
  short* WhP = (short*)(ws + 4194304ull);      //  8388608 B
  short* xbp = (short*)(ws + 12582912ull);     // 33554432 B
  u64* hqt   = (u64*)(ws + 46137344ull);       //  1048576 B (4 x 256KB tagged h)
  // zero tags every launch: stale tags from a prior replay must never alias this
  // run's expected tag sequence
  (void)hipMemsetAsync(hqt, 0, 1048576ull, stream);
  prep_w<<<24576, 256, 0, stream>>>(W, WxP, WhP);
  prep_x<<<8192, 256, 0, stream>>>(x, xbp);
  lstm_seq<<<NWG, 256, 0, stream>>>(xbp, WhP, WxP, bias, peep_i, peep_f, peep_o, hqt,
                                    (float*)d_out);
}

// Round 8
// 2734.426 us; speedup vs baseline: 2.7651x; 1.6884x over previous
//
#include <hip/hip_runtime.h>
#include <hip/hip_bf16.h>

// PeepholeLSTM: SEQ=512, BATCH=64, IN=512, HS=1024, FORGET_BIAS=0
// out = [hidden_seq (512*64*1024) | c_T (64*1024) | h_T (64*1024)] f32
//
// Round-8: round-7 fused structure; h-consume moved off the atomic path.
//  prep_w : W f32 -> WxP bf16 [128 g][64 kb][32 pc][8] + WhP bf16 [128 g][128 kb][32 pc][8]
//  prep_x : x f32 -> xbp bf16 [512 t][64 kb][64 m][8]
//  lstm_seq: 128 persistent WGs x 256. WG g owns hidden cols [8g,8g+8).
//    Publish: 1 tagged u64 atomic-exchange/lane (tag|2bf16; atomicity = tag-data consistent).
//    Consume: regular dwordx4 loads (2 tagged u64 each). First try = plain cached load
//    (XCD-L2 shareable, 16 WGs/XCD reuse); on tag mismatch retry with inline-asm
//    global_load_dwordx4 sc0 sc1 (bypass L1+L2, fresh at LLC) batched + vmcnt(0) +
//    sched_barrier (rule #18). Tags make stale caching safe. 8-deep buffer rotation.
//    Round-7 lesson: 4.2M u64 ATOMIC loads/step = atomic-path throughput wall (~9us/step,
//    85% VMEM stall). Regular loads: 2x fewer ops, streaming path, L2-shared common case.

#define SEQN 512
#define BATCH 64
#define INDIM 512
#define HSZ 1024
#define NWG 128
#define DEPTH 8

typedef __attribute__((ext_vector_type(8))) short s16x8;
typedef __attribute__((ext_vector_type(4))) float f32x4;
typedef __attribute__((ext_vector_type(2))) float f32x2;
typedef __attribute__((ext_vector_type(4))) int i32x4;
typedef unsigned long long u64;

__device__ __forceinline__ short f2bf(float f) {
  __hip_bfloat16 b = __float2bfloat16(f);
  short s;
  __builtin_memcpy(&s, &b, 2);
  return s;
}
__device__ __forceinline__ float sigf(float x) { return 1.f / (1.f + __expf(-x)); }
__device__ __forceinline__ float tanh_fast(float x) { return 2.f / (1.f + __expf(-2.f * x)) - 1.f; }

// ---------------------------------------------------------------------------
// prep_w: one thread per W element. col = gate*1024 + hidx; hidx = g*8+off; pc = off*4+gate.
__global__ __launch_bounds__(256) void prep_w(const float* __restrict__ W,
                                              short* __restrict__ WxP,
                                              short* __restrict__ WhP) {
  int idx = blockIdx.x * 256 + threadIdx.x;
  if (idx >= 1536 * 4096) return;
  int k = idx >> 12, col = idx & 4095;
  short b = f2bf(W[idx]);
  int gate = col >> 10, hidx = col & 1023;
  int g = hidx >> 3, off = hidx & 7;
  int pc = off * 4 + gate;
  if (k < 512) {
    WxP[(size_t)(((g * 64 + (k >> 3)) * 32 + pc) << 3) + (k & 7)] = b;
  } else {
    int kh = k - 512;
    WhP[(size_t)(((g * 128 + (kh >> 3)) * 32 + pc) << 3) + (kh & 7)] = b;
  }
}

// ---------------------------------------------------------------------------
// prep_x: x[t][m][k] f32 -> xbp[t][kb][m][8] bf16.
__global__ __launch_bounds__(256) void prep_x(const float* __restrict__ x,
                                              short* __restrict__ xbp) {
  int idx = blockIdx.x * 256 + threadIdx.x;
  if (idx >= SEQN * 64 * 64) return;
  int kb = idx & 63, m = (idx >> 6) & 63, t = idx >> 12;
  const float4* xp = reinterpret_cast<const float4*>(x + ((size_t)t * 64 + m) * 512 + kb * 8);
  float4 a = xp[0], c = xp[1];
  s16x8 v;
  v[0] = f2bf(a.x); v[1] = f2bf(a.y); v[2] = f2bf(a.z); v[3] = f2bf(a.w);
  v[4] = f2bf(c.x); v[5] = f2bf(c.y); v[6] = f2bf(c.z); v[7] = f2bf(c.w);
  reinterpret_cast<s16x8*>(xbp)[((size_t)t * 64 + kb) * 64 + m] = v;
}

// ---------------------------------------------------------------------------
// lstm_seq: 128 WGs x 256. Wave w: batch rows [16w,16w+16). Lane l: m = w*16+(l&15),
// q4 = l>>4, hidden cols c0 = 8g+q4, c1 = c0+4, all 4 gates (acc0[r]=gate r @ c0, acc1 @ c1).
// hqt[t&7][gsrc 0..127][m 0..63][j 0..3] u64 = tag(t)<<32 | h[8gsrc+j+4]<<16 | h[8gsrc+j].
__global__ __launch_bounds__(256, 1) void lstm_seq(const short* __restrict__ xbp,
                                                   const short* __restrict__ WhP,
                                                   const short* __restrict__ WxP,
                                                   const float* __restrict__ bias,
                                                   const float* __restrict__ peep_i,
                                                   const float* __restrict__ peep_f,
                                                   const float* __restrict__ peep_o,
                                                   u64* hqt,
                                                   float* __restrict__ out) {
  __shared__ short WhS[32768];   // 64KB [kb 128][pc 32][8]
  __shared__ short WxS[16384];   // 32KB [kb  64][pc 32][8]
  __shared__ float outS[512];    //  2KB
  int g = blockIdx.x;
  int tid = threadIdx.x, w = tid >> 6, l = tid & 63;
  {
    const s16x8* src = reinterpret_cast<const s16x8*>(WhP + (size_t)g * 32768);
    s16x8* dst = reinterpret_cast<s16x8*>(WhS);
#pragma unroll
    for (int i = 0; i < 16; ++i) dst[i * 256 + tid] = src[i * 256 + tid];
    const s16x8* src2 = reinterpret_cast<const s16x8*>(WxP + (size_t)g * 16384);
    s16x8* dst2 = reinterpret_cast<s16x8*>(WxS);
#pragma unroll
    for (int i = 0; i < 8; ++i) dst2[i * 256 + tid] = src2[i * 256 + tid];
  }
  int m = w * 16 + (l & 15), q4 = l >> 4, l15 = l & 15;
  int c0 = g * 8 + q4, c1 = c0 + 4;
  float bi0 = bias[c0], bj0 = bias[1024 + c0], bf0 = bias[2048 + c0], bo0 = bias[3072 + c0];
  float bi1 = bias[c1], bj1 = bias[1024 + c1], bf1 = bias[2048 + c1], bo1 = bias[3072 + c1];
  float pi0 = peep_i[c0], pf0 = peep_f[c0], po0 = peep_o[c0];
  float pi1 = peep_i[c1], pf1 = peep_f[c1], po1 = peep_o[c1];
  float cr0 = 0.f, cr1 = 0.f;
  s16x8* WhS16 = reinterpret_cast<s16x8*>(WhS);
  s16x8* WxS16 = reinterpret_cast<s16x8*>(WxS);
  __syncthreads();

// group G: 16 dwordx4/lane (= 32 tagged u64, 8 kb-blocks). Load i covers u64 j=(i&1)*2,+1
// at kb_=((G)*8+(i>>1))*4+q4. dwordx4 words: [0]=data j, [1]=tag j, [2]=data j+1, [3]=tag j+1.
#define LOADG(BANK, G)                                                                   \
  {                                                                                      \
    _Pragma("unroll") for (int i = 0; i < 16; ++i) {                                     \
      int kb_ = ((G) * 8 + (i >> 1)) * 4 + q4;                                           \
      BANK[i] = *reinterpret_cast<const i32x4*>(rdq + kb_ * 256 + m * 4 + (i & 1) * 2);  \
    }                                                                                    \
  }
// retry: bypass L1+L2 (sc0 sc1), fresh at LLC; batched issue + one drain + sched fence
#define RELOADG(BANK, G)                                                                 \
  {                                                                                      \
    _Pragma("unroll") for (int i = 0; i < 16; ++i) {                                     \
      int kb_ = ((G) * 8 + (i >> 1)) * 4 + q4;                                           \
      const u64* p_ = rdq + kb_ * 256 + m * 4 + (i & 1) * 2;                             \
      asm volatile("global_load_dwordx4 %0, %1, off sc0 sc1" : "=v"(BANK[i]) : "v"(p_)); \
    }                                                                                    \
    asm volatile("s_waitcnt vmcnt(0)" ::: "memory");                                     \
    __builtin_amdgcn_sched_barrier(0);                                                   \
  }
#define CHECKG(BANK, G)                                                                  \
  {                                                                                      \
    int guard = 0;                                                                       \
    while (true) {                                                                       \
      bool ok = true;                                                                    \
      _Pragma("unroll") for (int i = 0; i < 16; ++i) ok &=                               \
          ((unsigned)BANK[i][1] == (unsigned)t) & ((unsigned)BANK[i][3] == (unsigned)t); \
      if (__all((int)ok)) break;                                                         \
      if (++guard > (1 << 13)) break; /* fail loud, never hang */                        \
      RELOADG(BANK, G);                                                                  \
    }                                                                                    \
  }
#define MFMAG(BANK, G)                                                                   \
  {                                                                                      \
    _Pragma("unroll") for (int kk2 = 0; kk2 < 8; ++kk2) {                                \
      int kb_ = ((G) * 8 + kk2) * 4 + q4;                                                \
      unsigned d0 = (unsigned)BANK[kk2 * 2][0], d1 = (unsigned)BANK[kk2 * 2][2];         \
      unsigned d2 = (unsigned)BANK[kk2 * 2 + 1][0], d3 = (unsigned)BANK[kk2 * 2 + 1][2]; \
      union { unsigned u[4]; s16x8 v; } bu;                                              \
      bu.u[0] = (d0 & 0xFFFFu) | (d1 << 16);                                             \
      bu.u[1] = (d2 & 0xFFFFu) | (d3 << 16);                                             \
      bu.u[2] = (d0 >> 16) | (d1 & 0xFFFF0000u);                                         \
      bu.u[3] = (d2 >> 16) | (d3 & 0xFFFF0000u);                                        \
      s16x8 a0 = WhS16[kb_ * 32 + l15];                                                  \
      s16x8 a1 = WhS16[kb_ * 32 + 16 + l15];                                             \
      acc0 = __builtin_amdgcn_mfma_f32_16x16x32_bf16(a0, bu.v, acc0, 0, 0, 0);           \
      acc1 = __builtin_amdgcn_mfma_f32_16x16x32_bf16(a1, bu.v, acc1, 0, 0, 0);           \
    }                                                                                    \
  }

  for (int t = 0; t < SEQN; ++t) {
    f32x4 acc0 = {0.f, 0.f, 0.f, 0.f}, acc1 = {0.f, 0.f, 0.f, 0.f};
    // ---- x-projection (h-independent; fills the publish-visibility window) ----
    {
      const s16x8* xt = reinterpret_cast<const s16x8*>(xbp) + (size_t)t * 4096;
#pragma unroll 4
      for (int kk = 0; kk < 16; ++kk) {
        int kb = kk * 4 + q4;
        s16x8 bx = xt[kb * 64 + m];
        s16x8 a0 = WxS16[kb * 32 + l15];
        s16x8 a1 = WxS16[kb * 32 + 16 + l15];
        acc0 = __builtin_amdgcn_mfma_f32_16x16x32_bf16(a0, bx, acc0, 0, 0, 0);
        acc1 = __builtin_amdgcn_mfma_f32_16x16x32_bf16(a1, bx, acc1, 0, 0, 0);
      }
    }
    // ---- recurrent part: tagged-h consume, 4 groups, 2 reg banks ----
    if (t > 0) {
      const u64* rdq = hqt + (size_t)(t & (DEPTH - 1)) * 32768;
      i32x4 hA[16], hB[16];
      LOADG(hA, 0);
      LOADG(hB, 1);
      CHECKG(hA, 0);
      MFMAG(hA, 0);
      LOADG(hA, 2);
      CHECKG(hB, 1);
      MFMAG(hB, 1);
      LOADG(hB, 3);
      CHECKG(hA, 2);
      MFMAG(hA, 2);
      CHECKG(hB, 3);
      MFMAG(hB, 3);
    }
    // ---- elementwise (lane-local: all 4 gates of c0 and c1) ----
    float i0 = sigf(acc0[0] + bi0 + cr0 * pi0);
    float f0 = sigf(acc0[2] + bf0 + cr0 * pf0);
    float cn0 = f0 * cr0 + i0 * tanh_fast(acc0[1] + bj0);
    float o0 = sigf(acc0[3] + bo0 + cn0 * po0);
    float h0 = o0 * tanh_fast(cn0);
    cr0 = cn0;
    float i1 = sigf(acc1[0] + bi1 + cr1 * pi1);
    float f1 = sigf(acc1[2] + bf1 + cr1 * pf1);
    float cn1 = f1 * cr1 + i1 * tanh_fast(acc1[1] + bj1);
    float o1 = sigf(acc1[3] + bo1 + cn1 * po1);
    float h1 = o1 * tanh_fast(cn1);
    cr1 = cn1;
    // ---- publish tagged h_t (tag t+1) into buf (t+1)&7: ONE exchange/lane ----
    {
      u64 q = ((u64)(unsigned)(t + 1) << 32) |
              ((u64)(unsigned short)f2bf(h1) << 16) | (u64)(unsigned short)f2bf(h0);
      (void)__hip_atomic_exchange(
          hqt + (size_t)((t + 1) & (DEPTH - 1)) * 32768 + g * 256 + m * 4 + q4, q,
          __ATOMIC_RELAXED, __HIP_MEMORY_SCOPE_AGENT);
    }
    // ---- coalesced hidden_seq store via wave-local LDS stage ----
    outS[w * 128 + l15 * 8 + q4] = h0;
    outS[w * 128 + l15 * 8 + q4 + 4] = h1;
    {
      f32x2 v = *reinterpret_cast<f32x2*>(&outS[w * 128 + (l >> 2) * 8 + (l & 3) * 2]);
      int row = w * 16 + (l >> 2), col = g * 8 + (l & 3) * 2;
      __builtin_nontemporal_store(
          v, reinterpret_cast<f32x2*>(out + (size_t)t * 65536 + (size_t)row * 1024 + col));
    }
    if (t == SEQN - 1) {
      out[33554432ull + (size_t)m * 1024 + c0] = cn0;  // c_T
      out[33554432ull + (size_t)m * 1024 + c1] = cn1;
      out[33619968ull + (size_t)m * 1024 + c0] = h0;   // h_T
      out[33619968ull + (size_t)m * 1024 + c1] = h1;
    }
  }
#undef LOADG
#undef RELOADG
#undef CHECKG
#undef MFMAG
}

// ---------------------------------------------------------------------------
extern "C" void kernel_launch(void* const* d_in, const int* in_sizes, int n_in,
                              void* d_out, int out_size, void* d_ws, size_t ws_size,
                              hipStream_t stream) {
  const float* x      = (const float*)d_in[0];
  const float* W      = (const float*)d_in[1];
  const float* bias   = (const float*)d_in[2];
  const float* peep_i = (const float*)d_in[3];
  const float* peep_f = (const float*)d_in[4];
  const float* peep_o = (const float*)d_in[5];
  char* ws = (char*)d_ws;
  short* WxP = (short*)(ws);                   //  4194304 B
  short* WhP = (short*)(ws + 4194304ull);      //  8388608 B
  short* xbp = (short*)(ws + 12582912ull);     // 33554432 B
  u64* hqt   = (u64*)(ws + 46137344ull);       //  2097152 B (8 x 256KB tagged h)
  // zero tags every launch: stale tags from a prior replay must never alias this
  // run's expected tag sequence
  (void)hipMemsetAsync(hqt, 0, 2097152ull, stream);
  prep_w<<<24576, 256, 0, stream>>>(W, WxP, WhP);
  prep_x<<<8192, 256, 0, stream>>>(x, xbp);
  lstm_seq<<<NWG, 256, 0, stream>>>(xbp, WhP, WxP, bias, peep_i, peep_f, peep_o, hqt,
                                    (float*)d_out);
}

// Round 9
// 2586.595 us; speedup vs baseline: 2.9232x; 1.0572x over previous
//
#include <hip/hip_runtime.h>
#include <hip/hip_bf16.h>

// PeepholeLSTM: SEQ=512, BATCH=64, IN=512, HS=1024, FORGET_BIAS=0
// out = [hidden_seq (512*64*1024) | c_T (64*1024) | h_T (64*1024)] f32
//
// Round-9 = round-8 with DEPTH 8 -> 64.
//   Round-8 analysis: 128 WGs x 256KB tagged-h reads/step, all on the LLC-bypass path
//   = 32MB/step = 6.1 TB/s sustained at the LLC -> coherence-point BW wall.
//   The plain-load (L2-shared) fast path never fired: a slot reused every 8 steps is
//   still stale-resident in L2 (~2.5MB intervening < 4MB L2). At DEPTH=64, ~16MB flows
//   through L2 between slot reuses -> stale lines certainly evicted -> plain load
//   misses, L2 refills FRESH from LLC, 16 WGs/XCD share one fill (16x LLC traffic cut).
//   Tag mismatch still self-corrects via sc0sc1 retry (bounded downside = round-8 perf).
//
//  prep_w : W f32 -> WxP bf16 [128 g][64 kb][32 pc][8] + WhP bf16 [128 g][128 kb][32 pc][8]
//  prep_x : x f32 -> xbp bf16 [512 t][64 kb][64 m][8]
//  lstm_seq: 128 persistent WGs x 256. WG g owns hidden cols [8g,8g+8).
//    Publish: 1 tagged u64 atomic-exchange/lane (tag|2bf16; atomicity = tag-data consistent).
//    Consume: plain dwordx4 loads (L2-shareable) -> tag check -> sc0sc1 bypass retry.

#define SEQN 512
#define BATCH 64
#define INDIM 512
#define HSZ 1024
#define NWG 128
#define DEPTH 64

typedef __attribute__((ext_vector_type(8))) short s16x8;
typedef __attribute__((ext_vector_type(4))) float f32x4;
typedef __attribute__((ext_vector_type(2))) float f32x2;
typedef __attribute__((ext_vector_type(4))) int i32x4;
typedef unsigned long long u64;

__device__ __forceinline__ short f2bf(float f) {
  __hip_bfloat16 b = __float2bfloat16(f);
  short s;
  __builtin_memcpy(&s, &b, 2);
  return s;
}
__device__ __forceinline__ float sigf(float x) { return 1.f / (1.f + __expf(-x)); }
__device__ __forceinline__ float tanh_fast(float x) { return 2.f / (1.f + __expf(-2.f * x)) - 1.f; }

// ---------------------------------------------------------------------------
// prep_w: one thread per W element. col = gate*1024 + hidx; hidx = g*8+off; pc = off*4+gate.
__global__ __launch_bounds__(256) void prep_w(const float* __restrict__ W,
                                              short* __restrict__ WxP,
                                              short* __restrict__ WhP) {
  int idx = blockIdx.x * 256 + threadIdx.x;
  if (idx >= 1536 * 4096) return;
  int k = idx >> 12, col = idx & 4095;
  short b = f2bf(W[idx]);
  int gate = col >> 10, hidx = col & 1023;
  int g = hidx >> 3, off = hidx & 7;
  int pc = off * 4 + gate;
  if (k < 512) {
    WxP[(size_t)(((g * 64 + (k >> 3)) * 32 + pc) << 3) + (k & 7)] = b;
  } else {
    int kh = k - 512;
    WhP[(size_t)(((g * 128 + (kh >> 3)) * 32 + pc) << 3) + (kh & 7)] = b;
  }
}

// ---------------------------------------------------------------------------
// prep_x: x[t][m][k] f32 -> xbp[t][kb][m][8] bf16.
__global__ __launch_bounds__(256) void prep_x(const float* __restrict__ x,
                                              short* __restrict__ xbp) {
  int idx = blockIdx.x * 256 + threadIdx.x;
  if (idx >= SEQN * 64 * 64) return;
  int kb = idx & 63, m = (idx >> 6) & 63, t = idx >> 12;
  const float4* xp = reinterpret_cast<const float4*>(x + ((size_t)t * 64 + m) * 512 + kb * 8);
  float4 a = xp[0], c = xp[1];
  s16x8 v;
  v[0] = f2bf(a.x); v[1] = f2bf(a.y); v[2] = f2bf(a.z); v[3] = f2bf(a.w);
  v[4] = f2bf(c.x); v[5] = f2bf(c.y); v[6] = f2bf(c.z); v[7] = f2bf(c.w);
  reinterpret_cast<s16x8*>(xbp)[((size_t)t * 64 + kb) * 64 + m] = v;
}

// ---------------------------------------------------------------------------
// lstm_seq: 128 WGs x 256. Wave w: batch rows [16w,16w+16). Lane l: m = w*16+(l&15),
// q4 = l>>4, hidden cols c0 = 8g+q4, c1 = c0+4, all 4 gates (acc0[r]=gate r @ c0, acc1 @ c1).
// hqt[t&63][gsrc 0..127][m 0..63][j 0..3] u64 = tag(t)<<32 | h[8gsrc+j+4]<<16 | h[8gsrc+j].
__global__ __launch_bounds__(256, 1) void lstm_seq(const short* __restrict__ xbp,
                                                   const short* __restrict__ WhP,
                                                   const short* __restrict__ WxP,
                                                   const float* __restrict__ bias,
                                                   const float* __restrict__ peep_i,
                                                   const float* __restrict__ peep_f,
                                                   const float* __restrict__ peep_o,
                                                   u64* hqt,
                                                   float* __restrict__ out) {
  __shared__ short WhS[32768];   // 64KB [kb 128][pc 32][8]
  __shared__ short WxS[16384];   // 32KB [kb  64][pc 32][8]
  __shared__ float outS[512];    //  2KB
  int g = blockIdx.x;
  int tid = threadIdx.x, w = tid >> 6, l = tid & 63;
  {
    const s16x8* src = reinterpret_cast<const s16x8*>(WhP + (size_t)g * 32768);
    s16x8* dst = reinterpret_cast<s16x8*>(WhS);
#pragma unroll
    for (int i = 0; i < 16; ++i) dst[i * 256 + tid] = src[i * 256 + tid];
    const s16x8* src2 = reinterpret_cast<const s16x8*>(WxP + (size_t)g * 16384);
    s16x8* dst2 = reinterpret_cast<s16x8*>(WxS);
#pragma unroll
    for (int i = 0; i < 8; ++i) dst2[i * 256 + tid] = src2[i * 256 + tid];
  }
  int m = w * 16 + (l & 15), q4 = l >> 4, l15 = l & 15;
  int c0 = g * 8 + q4, c1 = c0 + 4;
  float bi0 = bias[c0], bj0 = bias[1024 + c0], bf0 = bias[2048 + c0], bo0 = bias[3072 + c0];
  float bi1 = bias[c1], bj1 = bias[1024 + c1], bf1 = bias[2048 + c1], bo1 = bias[3072 + c1];
  float pi0 = peep_i[c0], pf0 = peep_f[c0], po0 = peep_o[c0];
  float pi1 = peep_i[c1], pf1 = peep_f[c1], po1 = peep_o[c1];
  float cr0 = 0.f, cr1 = 0.f;
  s16x8* WhS16 = reinterpret_cast<s16x8*>(WhS);
  s16x8* WxS16 = reinterpret_cast<s16x8*>(WxS);
  __syncthreads();

// group G: 16 dwordx4/lane (= 32 tagged u64, 8 kb-blocks). Load i covers u64 j=(i&1)*2,+1
// at kb_=((G)*8+(i>>1))*4+q4. dwordx4 words: [0]=data j, [1]=tag j, [2]=data j+1, [3]=tag j+1.
#define LOADG(BANK, G)                                                                   \
  {                                                                                      \
    _Pragma("unroll") for (int i = 0; i < 16; ++i) {                                     \
      int kb_ = ((G) * 8 + (i >> 1)) * 4 + q4;                                           \
      BANK[i] = *reinterpret_cast<const i32x4*>(rdq + kb_ * 256 + m * 4 + (i & 1) * 2);  \
    }                                                                                    \
  }
// retry: bypass L1+L2 (sc0 sc1), fresh at LLC; batched issue + one drain + sched fence
#define RELOADG(BANK, G)                                                                 \
  {                                                                                      \
    _Pragma("unroll") for (int i = 0; i < 16; ++i) {                                     \
      int kb_ = ((G) * 8 + (i >> 1)) * 4 + q4;                                           \
      const u64* p_ = rdq + kb_ * 256 + m * 4 + (i & 1) * 2;                             \
      asm volatile("global_load_dwordx4 %0, %1, off sc0 sc1" : "=v"(BANK[i]) : "v"(p_)); \
    }                                                                                    \
    asm volatile("s_waitcnt vmcnt(0)" ::: "memory");                                     \
    __builtin_amdgcn_sched_barrier(0);                                                   \
  }
#define CHECKG(BANK, G)                                                                  \
  {                                                                                      \
    int guard = 0;                                                                       \
    while (true) {                                                                       \
      bool ok = true;                                                                    \
      _Pragma("unroll") for (int i = 0; i < 16; ++i) ok &=                               \
          ((unsigned)BANK[i][1] == (unsigned)t) & ((unsigned)BANK[i][3] == (unsigned)t); \
      if (__all((int)ok)) break;                                                         \
      if (++guard > (1 << 13)) break; /* fail loud, never hang */                        \
      RELOADG(BANK, G);                                                                  \
    }                                                                                    \
  }
#define MFMAG(BANK, G)                                                                   \
  {                                                                                      \
    _Pragma("unroll") for (int kk2 = 0; kk2 < 8; ++kk2) {                                \
      int kb_ = ((G) * 8 + kk2) * 4 + q4;                                                \
      unsigned d0 = (unsigned)BANK[kk2 * 2][0], d1 = (unsigned)BANK[kk2 * 2][2];         \
      unsigned d2 = (unsigned)BANK[kk2 * 2 + 1][0], d3 = (unsigned)BANK[kk2 * 2 + 1][2]; \
      union { unsigned u[4]; s16x8 v; } bu;                                              \
      bu.u[0] = (d0 & 0xFFFFu) | (d1 << 16);                                             \
      bu.u[1] = (d2 & 0xFFFFu) | (d3 << 16);                                             \
      bu.u[2] = (d0 >> 16) | (d1 & 0xFFFF0000u);                                         \
      bu.u[3] = (d2 >> 16) | (d3 & 0xFFFF0000u);                                        \
      s16x8 a0 = WhS16[kb_ * 32 + l15];                                                  \
      s16x8 a1 = WhS16[kb_ * 32 + 16 + l15];                                             \
      acc0 = __builtin_amdgcn_mfma_f32_16x16x32_bf16(a0, bu.v, acc0, 0, 0, 0);           \
      acc1 = __builtin_amdgcn_mfma_f32_16x16x32_bf16(a1, bu.v, acc1, 0, 0, 0);           \
    }                                                                                    \
  }

  for (int t = 0; t < SEQN; ++t) {
    f32x4 acc0 = {0.f, 0.f, 0.f, 0.f}, acc1 = {0.f, 0.f, 0.f, 0.f};
    // ---- x-projection (h-independent; fills the publish-visibility window) ----
    {
      const s16x8* xt = reinterpret_cast<const s16x8*>(xbp) + (size_t)t * 4096;
#pragma unroll 4
      for (int kk = 0; kk < 16; ++kk) {
        int kb = kk * 4 + q4;
        s16x8 bx = xt[kb * 64 + m];
        s16x8 a0 = WxS16[kb * 32 + l15];
        s16x8 a1 = WxS16[kb * 32 + 16 + l15];
        acc0 = __builtin_amdgcn_mfma_f32_16x16x32_bf16(a0, bx, acc0, 0, 0, 0);
        acc1 = __builtin_amdgcn_mfma_f32_16x16x32_bf16(a1, bx, acc1, 0, 0, 0);
      }
    }
    // ---- recurrent part: tagged-h consume, 4 groups, 2 reg banks ----
    if (t > 0) {
      const u64* rdq = hqt + (size_t)(t & (DEPTH - 1)) * 32768;
      i32x4 hA[16], hB[16];
      LOADG(hA, 0);
      LOADG(hB, 1);
      CHECKG(hA, 0);
      MFMAG(hA, 0);
      LOADG(hA, 2);
      CHECKG(hB, 1);
      MFMAG(hB, 1);
      LOADG(hB, 3);
      CHECKG(hA, 2);
      MFMAG(hA, 2);
      CHECKG(hB, 3);
      MFMAG(hB, 3);
    }
    // ---- elementwise (lane-local: all 4 gates of c0 and c1) ----
    float i0 = sigf(acc0[0] + bi0 + cr0 * pi0);
    float f0 = sigf(acc0[2] + bf0 + cr0 * pf0);
    float cn0 = f0 * cr0 + i0 * tanh_fast(acc0[1] + bj0);
    float o0 = sigf(acc0[3] + bo0 + cn0 * po0);
    float h0 = o0 * tanh_fast(cn0);
    cr0 = cn0;
    float i1 = sigf(acc1[0] + bi1 + cr1 * pi1);
    float f1 = sigf(acc1[2] + bf1 + cr1 * pf1);
    float cn1 = f1 * cr1 + i1 * tanh_fast(acc1[1] + bj1);
    float o1 = sigf(acc1[3] + bo1 + cn1 * po1);
    float h1 = o1 * tanh_fast(cn1);
    cr1 = cn1;
    // ---- publish tagged h_t (tag t+1) into buf (t+1)&63: ONE exchange/lane ----
    {
      u64 q = ((u64)(unsigned)(t + 1) << 32) |
              ((u64)(unsigned short)f2bf(h1) << 16) | (u64)(unsigned short)f2bf(h0);
      (void)__hip_atomic_exchange(
          hqt + (size_t)((t + 1) & (DEPTH - 1)) * 32768 + g * 256 + m * 4 + q4, q,
          __ATOMIC_RELAXED, __HIP_MEMORY_SCOPE_AGENT);
    }
    // ---- coalesced hidden_seq store via wave-local LDS stage ----
    outS[w * 128 + l15 * 8 + q4] = h0;
    outS[w * 128 + l15 * 8 + q4 + 4] = h1;
    {
      f32x2 v = *reinterpret_cast<f32x2*>(&outS[w * 128 + (l >> 2) * 8 + (l & 3) * 2]);
      int row = w * 16 + (l >> 2), col = g * 8 + (l & 3) * 2;
      __builtin_nontemporal_store(
          v, reinterpret_cast<f32x2*>(out + (size_t)t * 65536 + (size_t)row * 1024 + col));
    }
    if (t == SEQN - 1) {
      out[33554432ull + (size_t)m * 1024 + c0] = cn0;  // c_T
      out[33554432ull + (size_t)m * 1024 + c1] = cn1;
      out[33619968ull + (size_t)m * 1024 + c0] = h0;   // h_T
      out[33619968ull + (size_t)m * 1024 + c1] = h1;
    }
  }
#undef LOADG
#undef RELOADG
#undef CHECKG
#undef MFMAG
}

// ---------------------------------------------------------------------------
extern "C" void kernel_launch(void* const* d_in, const int* in_sizes, int n_in,
                              void* d_out, int out_size, void* d_ws, size_t ws_size,
                              hipStream_t stream) {
  const float* x      = (const float*)d_in[0];
  const float* W      = (const float*)d_in[1];
  const float* bias   = (const float*)d_in[2];
  const float* peep_i = (const float*)d_in[3];
  const float* peep_f = (const float*)d_in[4];
  const float* peep_o = (const float*)d_in[5];
  char* ws = (char*)d_ws;
  short* WxP = (short*)(ws);                   //  4194304 B
  short* WhP = (short*)(ws + 4194304ull);      //  8388608 B
  short* xbp = (short*)(ws + 12582912ull);     // 33554432 B
  u64* hqt   = (u64*)(ws + 46137344ull);       // 16777216 B (64 x 256KB tagged h slots)
  // zero tags every launch: stale tags from a prior replay must never alias this
  // run's expected tag sequence
  (void)hipMemsetAsync(hqt, 0, 16777216ull, stream);
  prep_w<<<24576, 256, 0, stream>>>(W, WxP, WhP);
  prep_x<<<8192, 256, 0, stream>>>(x, xbp);
  lstm_seq<<<NWG, 256, 0, stream>>>(xbp, WhP, WxP, bias, peep_i, peep_f, peep_o, hqt,
                                    (float*)d_out);
}